// Round 3
// baseline (423.778 us; speedup 1.0000x reference)
//
#include <hip/hip_runtime.h>
#include <hip/hip_bf16.h>
#include <cmath>

// LinearAttention: x[4,4096,1024] fp32 -> qkv -> elu+1 linear attention (16 heads, d=64) -> out proj.
// I/O is FP32 (per reference setup_inputs). Internal compute: bf16 MFMA with fp32 accumulate.
// Pipeline:
//   1) gemm_bt<0>: qkv = x @ w_qkv^T  (fp32 in, cvt->bf16 in staging, MFMA 16x16x32, 128x128 tile)
//      epilogue: q -> feat*scale -> Q[b,h,n,d] bf16; k -> feat*scale -> KT[b,h,d,n]; v -> VT[b,h,d,n]
//   2) kv_partial: kv[d,e] = sum_n k[n,d] v[n,e], K-split x4 fp32 partials (deterministic)
//   3) ksum: ksum[d] = sum_n k[n,d]
//   4) attn_out: att = (q @ kv) / (q . ksum + eps); denom via extra MFMA column; att bf16 [b,n,h*64+e]
//   5) gemm_bt<1>: y = att @ w_out^T + b_out  (A bf16, B fp32->bf16, out FP32)

typedef __bf16 bf16_t;
typedef __attribute__((ext_vector_type(8))) __bf16 bf16x8;
typedef __attribute__((ext_vector_type(4))) __bf16 bf16x4;
typedef __attribute__((ext_vector_type(4))) float f32x4;
typedef __attribute__((ext_vector_type(8))) float f32x8;

#define MFMA16(a, b, c) __builtin_amdgcn_mfma_f32_16x16x32_bf16((a), (b), (c), 0, 0, 0)

#define LDS_PITCH 72  // 64 + 8 pad; 144 B = 9 x 16B granules (keeps ds_read_b128 alignment)

__device__ __forceinline__ f32x4 zf4() { f32x4 z; z[0] = 0.f; z[1] = 0.f; z[2] = 0.f; z[3] = 0.f; return z; }

__device__ __forceinline__ float feat(float x) { return x > 0.f ? x + 1.f : expf(x); }

// Stage NR x 64 tile into padded LDS as bf16. Thread handles granule gidx = p*256+tid:
// row = gidx>>3, col-granule = gidx&7 (8 elements each).
template <int NR>
__device__ __forceinline__ void stage_f32(const float* g, int ld, bf16_t* lds, int tid)
{
#pragma unroll
    for (int p = 0; p < NR * 8 / 256; ++p) {
        const int gidx = p * 256 + tid;
        const int row = gidx >> 3;
        const int cp = gidx & 7;
        f32x8 f = *(const f32x8*)(g + row * ld + cp * 8);
        bf16x8 v;
#pragma unroll
        for (int t = 0; t < 8; ++t) v[t] = (bf16_t)f[t];
        *(bf16x8*)(lds + row * LDS_PITCH + cp * 8) = v;
    }
}

template <int NR>
__device__ __forceinline__ void stage_bf16(const bf16_t* g, int ld, bf16_t* lds, int tid)
{
#pragma unroll
    for (int p = 0; p < NR * 8 / 256; ++p) {
        const int gidx = p * 256 + tid;
        const int row = gidx >> 3;
        const int cp = gidx & 7;
        *(bf16x8*)(lds + row * LDS_PITCH + cp * 8) = *(const bf16x8*)(g + row * ld + cp * 8);
    }
}

// Read an A/B fragment (8 bf16, K-contiguous) from a padded LDS tile.
__device__ __forceinline__ bf16x8 read_frag(const bf16_t* lds, int row, int cg)
{
    return *(const bf16x8*)(lds + row * LDS_PITCH + cg * 8);
}

// C = A @ B^T, fp32 accum. Block 256 thr = 4 waves (2x2), tile 128x128, BK=64, 4x4 acc per wave.
// MODE 0: A,B fp32; epilogue -> Q(bf16), KT, VT.  MODE 1: A bf16, B fp32; out fp32 + fp32 bias.
template <int MODE>
__global__ __launch_bounds__(256, 2) void gemm_bt_kernel(
    const void* __restrict__ Av, const void* __restrict__ Bv, int K,
    void* __restrict__ out0, bf16_t* __restrict__ out1, bf16_t* __restrict__ out2,
    const float* __restrict__ bias)
{
    __shared__ __align__(16) bf16_t As[128 * LDS_PITCH];
    __shared__ __align__(16) bf16_t Bs[128 * LDS_PITCH];
    const int tid = threadIdx.x;
    const int l = tid & 63, w = tid >> 6;
    const int wm = w >> 1, wn = w & 1;
    const int quad = l >> 4, r16 = l & 15;
    const int m0 = blockIdx.y * 128;
    const int n0 = blockIdx.x * 128;

    f32x4 acc[4][4];
#pragma unroll
    for (int i = 0; i < 4; ++i)
#pragma unroll
        for (int j = 0; j < 4; ++j) acc[i][j] = zf4();

    for (int k0 = 0; k0 < K; k0 += 64) {
        if (MODE == 0) {
            stage_f32<128>((const float*)Av + (size_t)m0 * K + k0, K, As, tid);
            stage_f32<128>((const float*)Bv + (size_t)n0 * K + k0, K, Bs, tid);
        } else {
            stage_bf16<128>((const bf16_t*)Av + (size_t)m0 * K + k0, K, As, tid);
            stage_f32<128>((const float*)Bv + (size_t)n0 * K + k0, K, Bs, tid);
        }
        __syncthreads();
#pragma unroll
        for (int ks = 0; ks < 2; ++ks) {
            const int cg = ks * 4 + quad;
            bf16x8 af[4], bfr[4];
#pragma unroll
            for (int i = 0; i < 4; ++i) af[i] = read_frag(As, wm * 64 + i * 16 + r16, cg);
#pragma unroll
            for (int j = 0; j < 4; ++j) bfr[j] = read_frag(Bs, wn * 64 + j * 16 + r16, cg);
#pragma unroll
            for (int i = 0; i < 4; ++i)
#pragma unroll
                for (int j = 0; j < 4; ++j)
                    acc[i][j] = MFMA16(af[i], bfr[j], acc[i][j]);
        }
        __syncthreads();
    }

    // C/D layout (m89/m91-verified): col = lane&15, row = quad*4 + reg
    const float scale = 0.3535533905932738f;  // 64^-0.25
#pragma unroll
    for (int i = 0; i < 4; ++i) {
        const int mbase = m0 + wm * 64 + i * 16 + quad * 4;
#pragma unroll
        for (int j = 0; j < 4; ++j) {
            const int col = n0 + wn * 64 + j * 16 + r16;
            if (MODE == 1) {
                float* yp = (float*)out0;
                const float bb = bias[col];
#pragma unroll
                for (int r = 0; r < 4; ++r)
                    yp[(size_t)(mbase + r) * 1024 + col] = acc[i][j][r] + bb;
            } else {
                const int part = col >> 10;      // 0=q, 1=k, 2=v
                const int cc = col & 1023;
                const int hh = (mbase >> 12) * 16 + (cc >> 6);  // b*16 + h
                const int d = cc & 63;
                const int ntok = mbase & 4095;
                if (part == 0) {
                    bf16_t* qp = (bf16_t*)out0 + ((size_t)hh * 4096 + ntok) * 64 + d;
#pragma unroll
                    for (int r = 0; r < 4; ++r)
                        qp[(size_t)r * 64] = (bf16_t)(feat(acc[i][j][r]) * scale);
                } else {
                    // transposed [b,h,d,n]; 4 consecutive tokens -> 8B vector store
                    bf16_t* tp = (part == 1 ? out1 : out2) + ((size_t)hh * 64 + d) * 4096 + ntok;
                    bf16x4 pk;
#pragma unroll
                    for (int r = 0; r < 4; ++r) {
                        float v = acc[i][j][r];
                        if (part == 1) v = feat(v) * scale;
                        pk[r] = (bf16_t)v;
                    }
                    *(bf16x4*)tp = pk;
                }
            }
        }
    }
}

// kv partials: block = (head hh, K-split ksp). Wave w owns d-rows [w*16, w*16+16).
// kvp[hh][ksp][d][e] (fp32) = sum over 1024 tokens of k[n,d]*v[n,e].
__global__ __launch_bounds__(256, 2) void kv_partial_kernel(
    const bf16_t* __restrict__ KT, const bf16_t* __restrict__ VT, float* __restrict__ kvp)
{
    __shared__ __align__(16) bf16_t Ks[64 * LDS_PITCH];
    __shared__ __align__(16) bf16_t Vs[64 * LDS_PITCH];
    const int tid = threadIdx.x;
    const int l = tid & 63, w = tid >> 6;
    const int quad = l >> 4, r16 = l & 15;
    const int hh = blockIdx.x;   // 0..63 (b*16+h)
    const int ksp = blockIdx.y;  // 0..3
    const bf16_t* kb = KT + (size_t)hh * 64 * 4096 + ksp * 1024;
    const bf16_t* vb = VT + (size_t)hh * 64 * 4096 + ksp * 1024;

    f32x4 acc[4];
#pragma unroll
    for (int j = 0; j < 4; ++j) acc[j] = zf4();

    for (int k0 = 0; k0 < 1024; k0 += 64) {
        stage_bf16<64>(kb + k0, 4096, Ks, tid);
        stage_bf16<64>(vb + k0, 4096, Vs, tid);
        __syncthreads();
#pragma unroll
        for (int ks = 0; ks < 2; ++ks) {
            const int cg = ks * 4 + quad;
            bf16x8 af = read_frag(Ks, w * 16 + r16, cg);
#pragma unroll
            for (int j = 0; j < 4; ++j)
                acc[j] = MFMA16(af, read_frag(Vs, j * 16 + r16, cg), acc[j]);
        }
        __syncthreads();
    }

    float* ob = kvp + (size_t)(hh * 4 + ksp) * 4096;
    const int dbase = w * 16 + quad * 4;
#pragma unroll
    for (int j = 0; j < 4; ++j)
#pragma unroll
        for (int r = 0; r < 4; ++r)
            ob[(dbase + r) * 64 + j * 16 + r16] = acc[j][r];
}

// ksum[hh*64+d] = sum_n KT[hh][d][n]; one wave per row.
__global__ __launch_bounds__(256) void ksum_kernel(const bf16_t* __restrict__ KT, float* __restrict__ ksum)
{
    const int gw = blockIdx.x * 4 + (threadIdx.x >> 6);
    const int l = threadIdx.x & 63;
    const bf16_t* row = KT + (size_t)gw * 4096;
    float s = 0.f;
#pragma unroll
    for (int i = 0; i < 8; ++i) {
        bf16x8 v = *(const bf16x8*)(row + l * 8 + i * 512);
#pragma unroll
        for (int t = 0; t < 8; ++t) s += (float)v[t];
    }
#pragma unroll
    for (int off = 32; off > 0; off >>= 1) s += __shfl_down(s, off);
    if (l == 0) ksum[gw] = s;
}

// att = (q @ kv) / (q . ksum + eps); block = (head, 256-token tile); wave = 64 tokens.
// Q fragments read straight from global (coalesced 16B/lane, no LDS/barrier in K-loop).
// denom via one extra MFMA whose B-frag col0 = ksum (bf16), then quad-local __shfl broadcast.
__global__ __launch_bounds__(256, 2) void attn_out_kernel(
    const bf16_t* __restrict__ Q, const float* __restrict__ kvp, const float* __restrict__ ksum,
    bf16_t* __restrict__ att)
{
    __shared__ __align__(16) bf16_t kvT[64 * LDS_PITCH];  // [e][d]
    __shared__ __align__(16) bf16_t ksb[64];
    const int tid = threadIdx.x;
    const int l = tid & 63, w = tid >> 6;
    const int quad = l >> 4, r16 = l & 15;
    const int hh = blockIdx.x;
    const int b = hh >> 4, h = hh & 15;
    const int mt = blockIdx.y;  // 0..15

    {   // sum 4 K-split partials, transpose to [e][d], round to bf16
        const int e = tid >> 2;
        const int d0 = (tid & 3) * 16;
        const float* base = kvp + (size_t)hh * 4 * 4096;
#pragma unroll
        for (int dd = 0; dd < 16; ++dd) {
            const int d = d0 + dd;
            const float s = base[d * 64 + e] + base[4096 + d * 64 + e] +
                            base[8192 + d * 64 + e] + base[12288 + d * 64 + e];
            kvT[e * LDS_PITCH + d] = (bf16_t)s;
        }
        if (tid < 64) ksb[tid] = (bf16_t)ksum[hh * 64 + tid];
    }
    __syncthreads();

    f32x4 acc[4][4];
    f32x4 dacc[4];
#pragma unroll
    for (int i = 0; i < 4; ++i) {
        dacc[i] = zf4();
#pragma unroll
        for (int j = 0; j < 4; ++j) acc[i][j] = zf4();
    }

    const int m0w = mt * 256 + w * 64;
    const bf16_t* qb = Q + (size_t)hh * 4096 * 64;
#pragma unroll
    for (int ks = 0; ks < 2; ++ks) {
        bf16x8 kf = *(const bf16x8*)(ksb + ks * 32 + quad * 8);
        if (r16 != 0) {
#pragma unroll
            for (int t = 0; t < 8; ++t) kf[t] = (bf16_t)0.f;
        }
        bf16x8 bfr[4];
#pragma unroll
        for (int j = 0; j < 4; ++j)
            bfr[j] = *(const bf16x8*)(kvT + (j * 16 + r16) * LDS_PITCH + ks * 32 + quad * 8);
#pragma unroll
        for (int i = 0; i < 4; ++i) {
            const bf16_t* qp = qb + (size_t)(m0w + i * 16 + r16) * 64 + ks * 32 + quad * 8;
            const bf16x8 af = *(const bf16x8*)qp;
            dacc[i] = MFMA16(af, kf, dacc[i]);
#pragma unroll
            for (int j = 0; j < 4; ++j) acc[i][j] = MFMA16(af, bfr[j], acc[i][j]);
        }
    }

#pragma unroll
    for (int i = 0; i < 4; ++i) {
        float den[4];
#pragma unroll
        for (int r = 0; r < 4; ++r)
            den[r] = __shfl(dacc[i][r], l & 48) + 1e-6f;  // quad's col-0 lane holds my rows' denom
#pragma unroll
        for (int j = 0; j < 4; ++j) {
            const size_t colb = (size_t)h * 64 + j * 16 + r16;
#pragma unroll
            for (int r = 0; r < 4; ++r) {
                const int ntok = m0w + i * 16 + quad * 4 + r;
                att[((size_t)b * 4096 + ntok) * 1024 + colb] = (bf16_t)(acc[i][j][r] / den[r]);
            }
        }
    }
}

extern "C" void kernel_launch(void* const* d_in, const int* in_sizes, int n_in,
                              void* d_out, int out_size, void* d_ws, size_t ws_size,
                              hipStream_t stream)
{
    const float* x    = (const float*)d_in[0];  // [4,4096,1024] fp32
    const float* wqkv = (const float*)d_in[1];  // [3072,1024] fp32
    const float* wout = (const float*)d_in[2];  // [1024,1024] fp32
    const float* bout = (const float*)d_in[3];  // [1024] fp32
    float* y = (float*)d_out;                   // [4,4096,1024] fp32

    char* ws = (char*)d_ws;
    bf16_t* Q   = (bf16_t*)ws;                    // 16 Mi elems = 32 MiB  [b,h,n,d]
    bf16_t* KT  = Q + 16777216;                   // 32 MiB  [b,h,d,n]
    bf16_t* VT  = KT + 16777216;                  // 32 MiB  [b,h,d,n]
    float* kvp  = (float*)(ws + 100663296);       // 64*4*64*64 fp32 = 4 MiB
    float* ksum = (float*)(ws + 104857600);       // 4096 fp32
    bf16_t* att = KT;                             // alias: KT dead after stages 2-3

    gemm_bt_kernel<0><<<dim3(24, 128), 256, 0, stream>>>(x, wqkv, 1024, Q, KT, VT, nullptr);
    kv_partial_kernel<<<dim3(64, 4), 256, 0, stream>>>(KT, VT, kvp);
    ksum_kernel<<<1024, 256, 0, stream>>>(KT, ksum);
    attn_out_kernel<<<dim3(64, 16), 256, 0, stream>>>(Q, kvp, ksum, att);
    gemm_bt_kernel<1><<<dim3(8, 128), 256, 0, stream>>>(att, wout, 1024, y, nullptr, nullptr, bout);
}

// Round 4
// 343.918 us; speedup vs baseline: 1.2322x; 1.2322x over previous
//
#include <hip/hip_runtime.h>
#include <hip/hip_bf16.h>
#include <cmath>

// LinearAttention: x[4,4096,1024] fp32 -> qkv -> elu+1 linear attention (16 heads, d=64) -> out proj.
// I/O fp32; internal bf16 MFMA w/ fp32 accum.
// Round 4: one-time fp32->bf16 cvt pass, then pure-bf16 GEMMs with async global_load_lds
// width-16 staging + XOR swizzle (m97 structure). Middle stages unchanged from round 3.
// Pipeline:
//   0) cvt x->xb, w_qkv->wqkvb, w_out->woutb (bf16)
//   1) gemm_bt<0>: qkv = xb @ wqkvb^T; epilogue q->feat*scale->Q[b,h,n,d], k->KT[b,h,d,n], v->VT
//   2) kv_partial: kv[d,e] = sum_n k[n,d] v[n,e], K-split x4 fp32 partials
//   3) ksum: ksum[d] = sum_n k[n,d]
//   4) attn_out: att = (q @ kv) / (q . ksum + eps), denom via extra MFMA column
//   5) gemm_bt<1>: y = att @ woutb^T + b_out (fp32 out)

typedef __bf16 bf16_t;
typedef __attribute__((ext_vector_type(8))) __bf16 bf16x8;
typedef __attribute__((ext_vector_type(4))) __bf16 bf16x4;
typedef __attribute__((ext_vector_type(4))) float f32x4;
typedef __attribute__((ext_vector_type(8))) float f32x8;

#define MFMA16(a, b, c) __builtin_amdgcn_mfma_f32_16x16x32_bf16((a), (b), (c), 0, 0, 0)

#define LDS_PITCH 72  // padded pitch for the simple-staging (non-GEMM) kernels

__device__ __forceinline__ f32x4 zf4() { f32x4 z; z[0] = 0.f; z[1] = 0.f; z[2] = 0.f; z[3] = 0.f; return z; }

__device__ __forceinline__ float feat(float x) { return x > 0.f ? x + 1.f : expf(x); }

// ---------------- async staging (GEMM path) ----------------
__device__ __forceinline__ void gld_lds16(const bf16_t* src, bf16_t* dst)
{
    __builtin_amdgcn_global_load_lds(
        (__attribute__((address_space(1))) void*)const_cast<bf16_t*>(src),
        (__attribute__((address_space(3))) void*)dst, 16, 0, 0);
}

// Stage NR x 64 bf16 tile (row stride ld) into LDS, XOR-swizzled, via global_load_lds.
// LDS granule (row, sw) holds global granule (row, sw^(row&7)); readers apply the same XOR.
// Dest is wave-uniform base + lane*16 (HW rule); swizzle is applied on the SOURCE address.
template <int NR>
__device__ __forceinline__ void stage_async(const bf16_t* g, int ld, bf16_t* lds, int tid)
{
    const int w = tid >> 6, l = tid & 63;
    constexpr int CALLS = NR >> 5;  // per-wave calls; each call = 64 granules = 8 rows
#pragma unroll
    for (int p = 0; p < CALLS; ++p) {
        const int chunk = w * CALLS + p;         // wave-uniform
        const int gidx = chunk * 64 + l;
        const int row = gidx >> 3;
        const int cp = gidx & 7;
        const int c = cp ^ (row & 7);
        gld_lds16(g + row * ld + c * 8, lds + chunk * 512);
    }
}

// Fragment read from swizzled 64-pitch tile: 2-way LDS aliasing only (free, m136).
__device__ __forceinline__ bf16x8 read_frag_sw(const bf16_t* lds, int row, int cg)
{
    const int sw = cg ^ (row & 7);
    return *(const bf16x8*)(lds + row * 64 + sw * 8);
}

// ---------------- simple staging (middle kernels) ----------------
template <int NR>
__device__ __forceinline__ void stage_bf16(const bf16_t* g, int ld, bf16_t* lds, int tid)
{
#pragma unroll
    for (int p = 0; p < NR * 8 / 256; ++p) {
        const int gidx = p * 256 + tid;
        const int row = gidx >> 3;
        const int cp = gidx & 7;
        *(bf16x8*)(lds + row * LDS_PITCH + cp * 8) = *(const bf16x8*)(g + row * ld + cp * 8);
    }
}

__device__ __forceinline__ bf16x8 read_frag(const bf16_t* lds, int row, int cg)
{
    return *(const bf16x8*)(lds + row * LDS_PITCH + cg * 8);
}

// ---------------- fp32 -> bf16 convert ----------------
__global__ __launch_bounds__(256) void cvt_kernel(const float* __restrict__ src, bf16_t* __restrict__ dst)
{
    const size_t idx = ((size_t)blockIdx.x * 256 + threadIdx.x) * 8;
    f32x8 f = *(const f32x8*)(src + idx);
    bf16x8 v;
#pragma unroll
    for (int t = 0; t < 8; ++t) v[t] = (bf16_t)f[t];
    *(bf16x8*)(dst + idx) = v;
}

// ---------------- GEMM: C = A @ B^T, both bf16, fp32 accum ----------------
// Block 256 thr = 4 waves (2x2), tile 128x128, BK=64, 4x4 16x16x32 acc per wave.
// MODE 0: QKV epilogue (out0=Q, out1=KT, out2=VT, all bf16). MODE 1: fp32 out + fp32 bias.
template <int MODE>
__global__ __launch_bounds__(256, 2) void gemm_bt_kernel(
    const bf16_t* __restrict__ A, const bf16_t* __restrict__ B, int K,
    void* __restrict__ out0, bf16_t* __restrict__ out1, bf16_t* __restrict__ out2,
    const float* __restrict__ bias)
{
    __shared__ __align__(16) bf16_t As[128 * 64];
    __shared__ __align__(16) bf16_t Bs[128 * 64];
    const int tid = threadIdx.x;
    const int l = tid & 63, w = tid >> 6;
    const int wm = w >> 1, wn = w & 1;
    const int quad = l >> 4, r16 = l & 15;
    const int m0 = blockIdx.y * 128;
    const int n0 = blockIdx.x * 128;

    f32x4 acc[4][4];
#pragma unroll
    for (int i = 0; i < 4; ++i)
#pragma unroll
        for (int j = 0; j < 4; ++j) acc[i][j] = zf4();

    const bf16_t* Ab = A + (size_t)m0 * K;
    const bf16_t* Bb = B + (size_t)n0 * K;

    for (int k0 = 0; k0 < K; k0 += 64) {
        stage_async<128>(Ab + k0, K, As, tid);
        stage_async<128>(Bb + k0, K, Bs, tid);
        __syncthreads();
#pragma unroll
        for (int ks = 0; ks < 2; ++ks) {
            const int cg = ks * 4 + quad;
            bf16x8 af[4], bfr[4];
#pragma unroll
            for (int i = 0; i < 4; ++i) af[i] = read_frag_sw(As, wm * 64 + i * 16 + r16, cg);
#pragma unroll
            for (int j = 0; j < 4; ++j) bfr[j] = read_frag_sw(Bs, wn * 64 + j * 16 + r16, cg);
#pragma unroll
            for (int i = 0; i < 4; ++i)
#pragma unroll
                for (int j = 0; j < 4; ++j)
                    acc[i][j] = MFMA16(af[i], bfr[j], acc[i][j]);
        }
        __syncthreads();
    }

    // C/D layout (m89/m91-verified): col = lane&15, row = quad*4 + reg
    const float scale = 0.3535533905932738f;  // 64^-0.25
#pragma unroll
    for (int i = 0; i < 4; ++i) {
        const int mbase = m0 + wm * 64 + i * 16 + quad * 4;
#pragma unroll
        for (int j = 0; j < 4; ++j) {
            const int col = n0 + wn * 64 + j * 16 + r16;
            if (MODE == 1) {
                float* yp = (float*)out0;
                const float bb = bias[col];
#pragma unroll
                for (int r = 0; r < 4; ++r)
                    yp[(size_t)(mbase + r) * 1024 + col] = acc[i][j][r] + bb;
            } else {
                const int part = col >> 10;      // 0=q, 1=k, 2=v
                const int cc = col & 1023;
                const int hh = (mbase >> 12) * 16 + (cc >> 6);  // b*16 + h
                const int d = cc & 63;
                const int ntok = mbase & 4095;
                if (part == 0) {
                    bf16_t* qp = (bf16_t*)out0 + ((size_t)hh * 4096 + ntok) * 64 + d;
#pragma unroll
                    for (int r = 0; r < 4; ++r)
                        qp[(size_t)r * 64] = (bf16_t)(feat(acc[i][j][r]) * scale);
                } else {
                    // transposed [b,h,d,n]; 4 consecutive tokens -> 8B vector store
                    bf16_t* tp = (part == 1 ? out1 : out2) + ((size_t)hh * 64 + d) * 4096 + ntok;
                    bf16x4 pk;
#pragma unroll
                    for (int r = 0; r < 4; ++r) {
                        float v = acc[i][j][r];
                        if (part == 1) v = feat(v) * scale;
                        pk[r] = (bf16_t)v;
                    }
                    *(bf16x4*)tp = pk;
                }
            }
        }
    }
}

// kv partials: block = (head hh, K-split ksp). Wave w owns d-rows [w*16, w*16+16).
__global__ __launch_bounds__(256, 2) void kv_partial_kernel(
    const bf16_t* __restrict__ KT, const bf16_t* __restrict__ VT, float* __restrict__ kvp)
{
    __shared__ __align__(16) bf16_t Ks[64 * LDS_PITCH];
    __shared__ __align__(16) bf16_t Vs[64 * LDS_PITCH];
    const int tid = threadIdx.x;
    const int l = tid & 63, w = tid >> 6;
    const int quad = l >> 4, r16 = l & 15;
    const int hh = blockIdx.x;   // 0..63 (b*16+h)
    const int ksp = blockIdx.y;  // 0..3
    const bf16_t* kb = KT + (size_t)hh * 64 * 4096 + ksp * 1024;
    const bf16_t* vb = VT + (size_t)hh * 64 * 4096 + ksp * 1024;

    f32x4 acc[4];
#pragma unroll
    for (int j = 0; j < 4; ++j) acc[j] = zf4();

    for (int k0 = 0; k0 < 1024; k0 += 64) {
        stage_bf16<64>(kb + k0, 4096, Ks, tid);
        stage_bf16<64>(vb + k0, 4096, Vs, tid);
        __syncthreads();
#pragma unroll
        for (int ks = 0; ks < 2; ++ks) {
            const int cg = ks * 4 + quad;
            bf16x8 af = read_frag(Ks, w * 16 + r16, cg);
#pragma unroll
            for (int j = 0; j < 4; ++j)
                acc[j] = MFMA16(af, read_frag(Vs, j * 16 + r16, cg), acc[j]);
        }
        __syncthreads();
    }

    float* ob = kvp + (size_t)(hh * 4 + ksp) * 4096;
    const int dbase = w * 16 + quad * 4;
#pragma unroll
    for (int j = 0; j < 4; ++j)
#pragma unroll
        for (int r = 0; r < 4; ++r)
            ob[(dbase + r) * 64 + j * 16 + r16] = acc[j][r];
}

// ksum[hh*64+d] = sum_n KT[hh][d][n]; one wave per row.
__global__ __launch_bounds__(256) void ksum_kernel(const bf16_t* __restrict__ KT, float* __restrict__ ksum)
{
    const int gw = blockIdx.x * 4 + (threadIdx.x >> 6);
    const int l = threadIdx.x & 63;
    const bf16_t* row = KT + (size_t)gw * 4096;
    float s = 0.f;
#pragma unroll
    for (int i = 0; i < 8; ++i) {
        bf16x8 v = *(const bf16x8*)(row + l * 8 + i * 512);
#pragma unroll
        for (int t = 0; t < 8; ++t) s += (float)v[t];
    }
#pragma unroll
    for (int off = 32; off > 0; off >>= 1) s += __shfl_down(s, off);
    if (l == 0) ksum[gw] = s;
}

// att = (q @ kv) / (q . ksum + eps); block = (head, 256-token tile); wave = 64 tokens.
__global__ __launch_bounds__(256, 2) void attn_out_kernel(
    const bf16_t* __restrict__ Q, const float* __restrict__ kvp, const float* __restrict__ ksum,
    bf16_t* __restrict__ att)
{
    __shared__ __align__(16) bf16_t kvT[64 * LDS_PITCH];  // [e][d]
    __shared__ __align__(16) bf16_t ksb[64];
    const int tid = threadIdx.x;
    const int l = tid & 63, w = tid >> 6;
    const int quad = l >> 4, r16 = l & 15;
    const int hh = blockIdx.x;
    const int b = hh >> 4, h = hh & 15;
    const int mt = blockIdx.y;  // 0..15

    {   // sum 4 K-split partials, transpose to [e][d], round to bf16
        const int e = tid >> 2;
        const int d0 = (tid & 3) * 16;
        const float* base = kvp + (size_t)hh * 4 * 4096;
#pragma unroll
        for (int dd = 0; dd < 16; ++dd) {
            const int d = d0 + dd;
            const float s = base[d * 64 + e] + base[4096 + d * 64 + e] +
                            base[8192 + d * 64 + e] + base[12288 + d * 64 + e];
            kvT[e * LDS_PITCH + d] = (bf16_t)s;
        }
        if (tid < 64) ksb[tid] = (bf16_t)ksum[hh * 64 + tid];
    }
    __syncthreads();

    f32x4 acc[4][4];
    f32x4 dacc[4];
#pragma unroll
    for (int i = 0; i < 4; ++i) {
        dacc[i] = zf4();
#pragma unroll
        for (int j = 0; j < 4; ++j) acc[i][j] = zf4();
    }

    const int m0w = mt * 256 + w * 64;
    const bf16_t* qb = Q + (size_t)hh * 4096 * 64;
#pragma unroll
    for (int ks = 0; ks < 2; ++ks) {
        bf16x8 kf = *(const bf16x8*)(ksb + ks * 32 + quad * 8);
        if (r16 != 0) {
#pragma unroll
            for (int t = 0; t < 8; ++t) kf[t] = (bf16_t)0.f;
        }
        bf16x8 bfr[4];
#pragma unroll
        for (int j = 0; j < 4; ++j)
            bfr[j] = *(const bf16x8*)(kvT + (j * 16 + r16) * LDS_PITCH + ks * 32 + quad * 8);
#pragma unroll
        for (int i = 0; i < 4; ++i) {
            const bf16_t* qp = qb + (size_t)(m0w + i * 16 + r16) * 64 + ks * 32 + quad * 8;
            const bf16x8 af = *(const bf16x8*)qp;
            dacc[i] = MFMA16(af, kf, dacc[i]);
#pragma unroll
            for (int j = 0; j < 4; ++j) acc[i][j] = MFMA16(af, bfr[j], acc[i][j]);
        }
    }

#pragma unroll
    for (int i = 0; i < 4; ++i) {
        float den[4];
#pragma unroll
        for (int r = 0; r < 4; ++r)
            den[r] = __shfl(dacc[i][r], l & 48) + 1e-6f;  // quad's col-0 lane holds my rows' denom
#pragma unroll
        for (int j = 0; j < 4; ++j) {
            const size_t colb = (size_t)h * 64 + j * 16 + r16;
#pragma unroll
            for (int r = 0; r < 4; ++r) {
                const int ntok = m0w + i * 16 + quad * 4 + r;
                att[((size_t)b * 4096 + ntok) * 1024 + colb] = (bf16_t)(acc[i][j][r] / den[r]);
            }
        }
    }
}

extern "C" void kernel_launch(void* const* d_in, const int* in_sizes, int n_in,
                              void* d_out, int out_size, void* d_ws, size_t ws_size,
                              hipStream_t stream)
{
    const float* x    = (const float*)d_in[0];  // [4,4096,1024] fp32
    const float* wqkv = (const float*)d_in[1];  // [3072,1024] fp32
    const float* wout = (const float*)d_in[2];  // [1024,1024] fp32
    const float* bout = (const float*)d_in[3];  // [1024] fp32
    float* y = (float*)d_out;                   // [4,4096,1024] fp32

    char* ws = (char*)d_ws;
    bf16_t* xb    = (bf16_t*)ws;                          // 32 MiB  [16384,1024]
    bf16_t* wqkvb = (bf16_t*)(ws + (size_t)32 * 1048576); //  6 MiB  [3072,1024]
    bf16_t* woutb = (bf16_t*)(ws + (size_t)38 * 1048576); //  2 MiB  [1024,1024]
    bf16_t* Q     = (bf16_t*)(ws + (size_t)40 * 1048576); // 32 MiB  [b,h,n,d]
    bf16_t* KT    = (bf16_t*)(ws + (size_t)72 * 1048576); // 32 MiB  [b,h,d,n]
    bf16_t* VT    = (bf16_t*)(ws + (size_t)104 * 1048576);// 32 MiB  [b,h,d,n]  (end: 136 MiB)
    float* kvp    = (float*)ws;                           // aliases xb[0,4MiB) — xb dead after gemm<0>
    float* ksum   = (float*)(ws + (size_t)4 * 1048576);   // aliases xb[4MiB,+16KiB)
    bf16_t* att   = KT;                                   // KT dead after ksum

    cvt_kernel<<<8192, 256, 0, stream>>>(x, xb);          // 16 Mi elems
    cvt_kernel<<<1536, 256, 0, stream>>>(wqkv, wqkvb);    //  3 Mi elems
    cvt_kernel<<<512, 256, 0, stream>>>(wout, woutb);     //  1 Mi elems

    gemm_bt_kernel<0><<<dim3(24, 128), 256, 0, stream>>>(xb, wqkvb, 1024, Q, KT, VT, nullptr);
    kv_partial_kernel<<<dim3(64, 4), 256, 0, stream>>>(KT, VT, kvp);
    ksum_kernel<<<1024, 256, 0, stream>>>(KT, ksum);
    attn_out_kernel<<<dim3(64, 16), 256, 0, stream>>>(Q, kvp, ksum, att);
    gemm_bt_kernel<1><<<dim3(8, 128), 256, 0, stream>>>(att, woutb, 1024, y, nullptr, nullptr, bout);
}

// Round 5
// 326.721 us; speedup vs baseline: 1.2971x; 1.0526x over previous
//
#include <hip/hip_runtime.h>
#include <hip/hip_bf16.h>
#include <cmath>

// LinearAttention: x[4,4096,1024] fp32 -> qkv -> elu+1 linear attention (16 heads, d=64) -> out proj.
// I/O fp32; internal bf16 MFMA w/ fp32 accum.
// Round 5: kv_partial emits kv^T ([e][d]) + fused ksum partials (ones-MFMA); kvfix reduces
// partials to bf16 once; attn_out preamble fully coalesced; GEMM launch_bounds 2->3 blocks/CU.
// Pipeline:
//   0) cvt x->xb, w_qkv->wqkvb, w_out->woutb (bf16)
//   1) gemm_bt<0>: qkv = xb @ wqkvb^T; epilogue q->feat*scale->Q[b,h,n,d], k->KT[b,h,d,n], v->VT
//   2) kv_partial: kvp[hh][ksp][e][d] = sum_n v[n,e] k[n,d]; ksp[hh][ksp][d] = sum_n k[n,d]
//   3) kvfix: kvb[hh][e][d] (bf16) = sum_ksp kvp; ksumb[hh][d] (bf16) = sum_ksp ksp
//   4) attn_out: att = (q @ kv) / (q . ksum + eps), denom via extra MFMA column
//   5) gemm_bt<1>: y = att @ woutb^T + b_out (fp32 out)

typedef __bf16 bf16_t;
typedef __attribute__((ext_vector_type(8))) __bf16 bf16x8;
typedef __attribute__((ext_vector_type(4))) __bf16 bf16x4;
typedef __attribute__((ext_vector_type(4))) float f32x4;
typedef __attribute__((ext_vector_type(8))) float f32x8;

#define MFMA16(a, b, c) __builtin_amdgcn_mfma_f32_16x16x32_bf16((a), (b), (c), 0, 0, 0)

#define LDS_PITCH 72  // padded pitch for the simple-staging (non-GEMM) kernels

__device__ __forceinline__ f32x4 zf4() { f32x4 z; z[0] = 0.f; z[1] = 0.f; z[2] = 0.f; z[3] = 0.f; return z; }

__device__ __forceinline__ float feat(float x) { return x > 0.f ? x + 1.f : expf(x); }

// ---------------- async staging (GEMM path) ----------------
__device__ __forceinline__ void gld_lds16(const bf16_t* src, bf16_t* dst)
{
    __builtin_amdgcn_global_load_lds(
        (__attribute__((address_space(1))) void*)const_cast<bf16_t*>(src),
        (__attribute__((address_space(3))) void*)dst, 16, 0, 0);
}

// Stage NR x 64 bf16 tile (row stride ld) into LDS, XOR-swizzled, via global_load_lds.
// LDS granule (row, sw) holds global granule (row, sw^(row&7)); readers apply the same XOR.
template <int NR>
__device__ __forceinline__ void stage_async(const bf16_t* g, int ld, bf16_t* lds, int tid)
{
    const int w = tid >> 6, l = tid & 63;
    constexpr int CALLS = NR >> 5;  // per-wave calls; each call = 64 granules = 8 rows
#pragma unroll
    for (int p = 0; p < CALLS; ++p) {
        const int chunk = w * CALLS + p;         // wave-uniform
        const int gidx = chunk * 64 + l;
        const int row = gidx >> 3;
        const int cp = gidx & 7;
        const int c = cp ^ (row & 7);
        gld_lds16(g + row * ld + c * 8, lds + chunk * 512);
    }
}

// Fragment read from swizzled 64-pitch tile: 2-way LDS aliasing only (free, m136).
__device__ __forceinline__ bf16x8 read_frag_sw(const bf16_t* lds, int row, int cg)
{
    const int sw = cg ^ (row & 7);
    return *(const bf16x8*)(lds + row * 64 + sw * 8);
}

// ---------------- simple staging (middle kernels) ----------------
template <int NR>
__device__ __forceinline__ void stage_bf16(const bf16_t* g, int ld, bf16_t* lds, int tid)
{
#pragma unroll
    for (int p = 0; p < NR * 8 / 256; ++p) {
        const int gidx = p * 256 + tid;
        const int row = gidx >> 3;
        const int cp = gidx & 7;
        *(bf16x8*)(lds + row * LDS_PITCH + cp * 8) = *(const bf16x8*)(g + row * ld + cp * 8);
    }
}

__device__ __forceinline__ bf16x8 read_frag(const bf16_t* lds, int row, int cg)
{
    return *(const bf16x8*)(lds + row * LDS_PITCH + cg * 8);
}

// ---------------- fp32 -> bf16 convert ----------------
__global__ __launch_bounds__(256) void cvt_kernel(const float* __restrict__ src, bf16_t* __restrict__ dst)
{
    const size_t idx = ((size_t)blockIdx.x * 256 + threadIdx.x) * 8;
    f32x8 f = *(const f32x8*)(src + idx);
    bf16x8 v;
#pragma unroll
    for (int t = 0; t < 8; ++t) v[t] = (bf16_t)f[t];
    *(bf16x8*)(dst + idx) = v;
}

// ---------------- GEMM: C = A @ B^T, both bf16, fp32 accum ----------------
// Block 256 thr = 4 waves (2x2), tile 128x128, BK=64, 4x4 16x16x32 acc per wave.
// MODE 0: QKV epilogue (out0=Q, out1=KT, out2=VT, all bf16). MODE 1: fp32 out + fp32 bias.
template <int MODE>
__global__ __launch_bounds__(256, 3) void gemm_bt_kernel(
    const bf16_t* __restrict__ A, const bf16_t* __restrict__ B, int K,
    void* __restrict__ out0, bf16_t* __restrict__ out1, bf16_t* __restrict__ out2,
    const float* __restrict__ bias)
{
    __shared__ __align__(16) bf16_t As[128 * 64];
    __shared__ __align__(16) bf16_t Bs[128 * 64];
    const int tid = threadIdx.x;
    const int l = tid & 63, w = tid >> 6;
    const int wm = w >> 1, wn = w & 1;
    const int quad = l >> 4, r16 = l & 15;
    const int m0 = blockIdx.y * 128;
    const int n0 = blockIdx.x * 128;

    f32x4 acc[4][4];
#pragma unroll
    for (int i = 0; i < 4; ++i)
#pragma unroll
        for (int j = 0; j < 4; ++j) acc[i][j] = zf4();

    const bf16_t* Ab = A + (size_t)m0 * K;
    const bf16_t* Bb = B + (size_t)n0 * K;

    for (int k0 = 0; k0 < K; k0 += 64) {
        stage_async<128>(Ab + k0, K, As, tid);
        stage_async<128>(Bb + k0, K, Bs, tid);
        __syncthreads();
#pragma unroll
        for (int ks = 0; ks < 2; ++ks) {
            const int cg = ks * 4 + quad;
            bf16x8 af[4], bfr[4];
#pragma unroll
            for (int i = 0; i < 4; ++i) af[i] = read_frag_sw(As, wm * 64 + i * 16 + r16, cg);
#pragma unroll
            for (int j = 0; j < 4; ++j) bfr[j] = read_frag_sw(Bs, wn * 64 + j * 16 + r16, cg);
#pragma unroll
            for (int i = 0; i < 4; ++i)
#pragma unroll
                for (int j = 0; j < 4; ++j)
                    acc[i][j] = MFMA16(af[i], bfr[j], acc[i][j]);
        }
        __syncthreads();
    }

    // C/D layout (m89/m91-verified): col = lane&15, row = quad*4 + reg
    const float scale = 0.3535533905932738f;  // 64^-0.25
#pragma unroll
    for (int i = 0; i < 4; ++i) {
        const int mbase = m0 + wm * 64 + i * 16 + quad * 4;
#pragma unroll
        for (int j = 0; j < 4; ++j) {
            const int col = n0 + wn * 64 + j * 16 + r16;
            if (MODE == 1) {
                float* yp = (float*)out0;
                const float bb = bias[col];
#pragma unroll
                for (int r = 0; r < 4; ++r)
                    yp[(size_t)(mbase + r) * 1024 + col] = acc[i][j][r] + bb;
            } else {
                const int part = col >> 10;      // 0=q, 1=k, 2=v
                const int cc = col & 1023;
                const int hh = (mbase >> 12) * 16 + (cc >> 6);  // b*16 + h
                const int d = cc & 63;
                const int ntok = mbase & 4095;
                if (part == 0) {
                    bf16_t* qp = (bf16_t*)out0 + ((size_t)hh * 4096 + ntok) * 64 + d;
#pragma unroll
                    for (int r = 0; r < 4; ++r)
                        qp[(size_t)r * 64] = (bf16_t)(feat(acc[i][j][r]) * scale);
                } else {
                    // transposed [b,h,d,n]; 4 consecutive tokens -> 8B vector store
                    bf16_t* tp = (part == 1 ? out1 : out2) + ((size_t)hh * 64 + d) * 4096 + ntok;
                    bf16x4 pk;
#pragma unroll
                    for (int r = 0; r < 4; ++r) {
                        float v = acc[i][j][r];
                        if (part == 1) v = feat(v) * scale;
                        pk[r] = (bf16_t)v;
                    }
                    *(bf16x4*)tp = pk;
                }
            }
        }
    }
}

// kv partials + ksum partials: block = (head hh, K-split ksp). Wave w owns e-rows [w*16, w*16+16).
// kvp[hh][ksp][e][d] = sum_n v[n,e] k[n,d]  (A=V-frag, B=K-frag -> C[e][d] directly).
// ksp[hh][ksp][d]    = sum_n k[n,d]         (wave 0 only: A=ones -> every C row = column sums).
__global__ __launch_bounds__(256, 2) void kv_partial_kernel(
    const bf16_t* __restrict__ KT, const bf16_t* __restrict__ VT,
    float* __restrict__ kvp, float* __restrict__ ksp_out)
{
    __shared__ __align__(16) bf16_t Ks[64 * LDS_PITCH];
    __shared__ __align__(16) bf16_t Vs[64 * LDS_PITCH];
    const int tid = threadIdx.x;
    const int l = tid & 63, w = tid >> 6;
    const int quad = l >> 4, r16 = l & 15;
    const int hh = blockIdx.x;   // 0..63 (b*16+h)
    const int ksp = blockIdx.y;  // 0..3
    const bf16_t* kb = KT + (size_t)hh * 64 * 4096 + ksp * 1024;
    const bf16_t* vb = VT + (size_t)hh * 64 * 4096 + ksp * 1024;

    bf16x8 ones;
#pragma unroll
    for (int t = 0; t < 8; ++t) ones[t] = (bf16_t)1.0f;

    f32x4 acc[4], accks[4];
#pragma unroll
    for (int j = 0; j < 4; ++j) { acc[j] = zf4(); accks[j] = zf4(); }

    for (int k0 = 0; k0 < 1024; k0 += 64) {
        stage_bf16<64>(kb + k0, 4096, Ks, tid);
        stage_bf16<64>(vb + k0, 4096, Vs, tid);
        __syncthreads();
#pragma unroll
        for (int ks = 0; ks < 2; ++ks) {
            const int cg = ks * 4 + quad;
            bf16x8 af = read_frag(Vs, w * 16 + r16, cg);  // A = V (m-index = e)
            bf16x8 bk[4];
#pragma unroll
            for (int j = 0; j < 4; ++j) bk[j] = read_frag(Ks, j * 16 + r16, cg);  // B = K (n-index = d)
#pragma unroll
            for (int j = 0; j < 4; ++j) acc[j] = MFMA16(af, bk[j], acc[j]);
            if (w == 0) {
#pragma unroll
                for (int j = 0; j < 4; ++j) accks[j] = MFMA16(ones, bk[j], accks[j]);
            }
        }
        __syncthreads();
    }

    float* ob = kvp + (size_t)(hh * 4 + ksp) * 4096;
    const int ebase = w * 16 + quad * 4;
#pragma unroll
    for (int j = 0; j < 4; ++j)
#pragma unroll
        for (int r = 0; r < 4; ++r)
            ob[(ebase + r) * 64 + j * 16 + r16] = acc[j][r];

    if (w == 0 && quad == 0) {
        float* kso = ksp_out + (size_t)(hh * 4 + ksp) * 64;
#pragma unroll
        for (int j = 0; j < 4; ++j) kso[j * 16 + r16] = accks[j][0];  // all C rows identical
    }
}

// Reduce 4 K-split partials once: kvb[hh][e][d] bf16, ksumb[hh][d] bf16.
__global__ __launch_bounds__(256) void kvfix_kernel(
    const float* __restrict__ kvp, const float* __restrict__ ksp,
    bf16_t* __restrict__ kvb, bf16_t* __restrict__ ksumb)
{
    const int hh = blockIdx.x, t = threadIdx.x;
    const float* base = kvp + (size_t)hh * 4 * 4096;
    const int off = t * 16;
    bf16x8 o[2];
#pragma unroll
    for (int c = 0; c < 4; ++c) {
        f32x4 s = *(const f32x4*)(base + off + c * 4);
        s += *(const f32x4*)(base + 4096 + off + c * 4);
        s += *(const f32x4*)(base + 8192 + off + c * 4);
        s += *(const f32x4*)(base + 12288 + off + c * 4);
#pragma unroll
        for (int r = 0; r < 4; ++r) o[c >> 1][(c & 1) * 4 + r] = (bf16_t)s[r];
    }
    *(bf16x8*)(kvb + (size_t)hh * 4096 + off) = o[0];
    *(bf16x8*)(kvb + (size_t)hh * 4096 + off + 8) = o[1];
    if (t < 64) {
        const float* kb = ksp + (size_t)hh * 4 * 64;
        ksumb[(size_t)hh * 64 + t] = (bf16_t)(kb[t] + kb[64 + t] + kb[128 + t] + kb[192 + t]);
    }
}

// att = (q @ kv) / (q . ksum + eps); block = (head, 256-token tile); wave = 64 tokens.
__global__ __launch_bounds__(256, 2) void attn_out_kernel(
    const bf16_t* __restrict__ Q, const bf16_t* __restrict__ kvb, const bf16_t* __restrict__ ksumb,
    bf16_t* __restrict__ att)
{
    __shared__ __align__(16) bf16_t kvT[64 * LDS_PITCH];  // [e][d]
    __shared__ __align__(16) bf16_t ksb[64];
    const int tid = threadIdx.x;
    const int l = tid & 63, w = tid >> 6;
    const int quad = l >> 4, r16 = l & 15;
    const int hh = blockIdx.x;
    const int b = hh >> 4, h = hh & 15;
    const int mt = blockIdx.y;  // 0..15

    {   // coalesced preamble: kvb[hh] (8KB) -> padded LDS; ksumb -> ksb
        const int e = tid >> 2, d0 = (tid & 3) * 16;
        const bf16_t* kvbh = kvb + (size_t)hh * 4096;
        *(bf16x8*)(kvT + e * LDS_PITCH + d0)     = *(const bf16x8*)(kvbh + e * 64 + d0);
        *(bf16x8*)(kvT + e * LDS_PITCH + d0 + 8) = *(const bf16x8*)(kvbh + e * 64 + d0 + 8);
        if (tid < 64) ksb[tid] = ksumb[(size_t)hh * 64 + tid];
    }
    __syncthreads();

    f32x4 acc[4][4];
    f32x4 dacc[4];
#pragma unroll
    for (int i = 0; i < 4; ++i) {
        dacc[i] = zf4();
#pragma unroll
        for (int j = 0; j < 4; ++j) acc[i][j] = zf4();
    }

    const int m0w = mt * 256 + w * 64;
    const bf16_t* qb = Q + (size_t)hh * 4096 * 64;
#pragma unroll
    for (int ks = 0; ks < 2; ++ks) {
        bf16x8 kf = *(const bf16x8*)(ksb + ks * 32 + quad * 8);
        if (r16 != 0) {
#pragma unroll
            for (int t = 0; t < 8; ++t) kf[t] = (bf16_t)0.f;
        }
        bf16x8 bfr[4];
#pragma unroll
        for (int j = 0; j < 4; ++j)
            bfr[j] = *(const bf16x8*)(kvT + (j * 16 + r16) * LDS_PITCH + ks * 32 + quad * 8);
#pragma unroll
        for (int i = 0; i < 4; ++i) {
            const bf16_t* qp = qb + (size_t)(m0w + i * 16 + r16) * 64 + ks * 32 + quad * 8;
            const bf16x8 af = *(const bf16x8*)qp;
            dacc[i] = MFMA16(af, kf, dacc[i]);
#pragma unroll
            for (int j = 0; j < 4; ++j) acc[i][j] = MFMA16(af, bfr[j], acc[i][j]);
        }
    }

#pragma unroll
    for (int i = 0; i < 4; ++i) {
        float den[4];
#pragma unroll
        for (int r = 0; r < 4; ++r)
            den[r] = __shfl(dacc[i][r], l & 48) + 1e-6f;  // quad's col-0 lane holds my rows' denom
#pragma unroll
        for (int j = 0; j < 4; ++j) {
            const size_t colb = (size_t)h * 64 + j * 16 + r16;
#pragma unroll
            for (int r = 0; r < 4; ++r) {
                const int ntok = m0w + i * 16 + quad * 4 + r;
                att[((size_t)b * 4096 + ntok) * 1024 + colb] = (bf16_t)(acc[i][j][r] / den[r]);
            }
        }
    }
}

extern "C" void kernel_launch(void* const* d_in, const int* in_sizes, int n_in,
                              void* d_out, int out_size, void* d_ws, size_t ws_size,
                              hipStream_t stream)
{
    const float* x    = (const float*)d_in[0];  // [4,4096,1024] fp32
    const float* wqkv = (const float*)d_in[1];  // [3072,1024] fp32
    const float* wout = (const float*)d_in[2];  // [1024,1024] fp32
    const float* bout = (const float*)d_in[3];  // [1024] fp32
    float* y = (float*)d_out;                   // [4,4096,1024] fp32

    char* ws = (char*)d_ws;
    bf16_t* xb    = (bf16_t*)ws;                          // 32 MiB  [16384,1024]
    bf16_t* wqkvb = (bf16_t*)(ws + (size_t)32 * 1048576); //  6 MiB  [3072,1024]
    bf16_t* woutb = (bf16_t*)(ws + (size_t)38 * 1048576); //  2 MiB  [1024,1024]
    bf16_t* Q     = (bf16_t*)(ws + (size_t)40 * 1048576); // 32 MiB  [b,h,n,d]
    bf16_t* KT    = (bf16_t*)(ws + (size_t)72 * 1048576); // 32 MiB  [b,h,d,n]
    bf16_t* VT    = (bf16_t*)(ws + (size_t)104 * 1048576);// 32 MiB  [b,h,d,n]  (end: 136 MiB)
    // aliases into xb region (xb dead after gemm<0>):
    float* kvp    = (float*)ws;                           // 4 MiB   [hh][4][e][d]
    float* ksp    = (float*)(ws + (size_t)4 * 1048576);   // 64 KiB  [hh][4][d]
    bf16_t* kvb   = (bf16_t*)(ws + (size_t)5 * 1048576);  // 512 KiB [hh][e][d]
    bf16_t* ksumb = (bf16_t*)(ws + (size_t)6 * 1048576);  // 8 KiB   [hh][d]
    bf16_t* att   = KT;                                   // KT dead after kv_partial

    cvt_kernel<<<8192, 256, 0, stream>>>(x, xb);          // 16 Mi elems
    cvt_kernel<<<1536, 256, 0, stream>>>(wqkv, wqkvb);    //  3 Mi elems
    cvt_kernel<<<512, 256, 0, stream>>>(wout, woutb);     //  1 Mi elems

    gemm_bt_kernel<0><<<dim3(24, 128), 256, 0, stream>>>(xb, wqkvb, 1024, Q, KT, VT, nullptr);
    kv_partial_kernel<<<dim3(64, 4), 256, 0, stream>>>(KT, VT, kvp, ksp);
    kvfix_kernel<<<64, 256, 0, stream>>>(kvp, ksp, kvb, ksumb);
    attn_out_kernel<<<dim3(64, 16), 256, 0, stream>>>(Q, kvb, ksumb, att);
    gemm_bt_kernel<1><<<dim3(8, 128), 256, 0, stream>>>(att, woutb, 1024, y, nullptr, nullptr, bout);
}